// Round 9
// baseline (125.112 us; speedup 1.0000x reference)
//
#include <hip/hip_runtime.h>

// IntraSentenceAttention, MFMA bf16, pair-tile iterations + i-doubling.
// out[b,i,:] = m_i * sum_j e_ij x[b,j,:] / (sum_j e_ij + EPS)
//   e_ij = exp(dot(x_i,x_j) + min(i-j,10)) * m_j
// B=32, T=1024, D=128. Scores <= ~12.3 -> no online rescale needed.
//
// Structure: wave = (i-half h, j-parity p). Iteration processes a PAIR of
// j-tiles: p=0 waves compute the even member, p=1 the odd member -> all 4
// waves busy every iteration AND each wave owns 32 i-rows (aq[2]/acc[2]),
// so every A-operand LDS/global read feeds 2 MFMAs (halved read traffic).
// Stage-1 A-frags (K rows) come straight from global bf16 Xb (L2-resident,
// VMEM pipe idle); only K^T is staged in LDS (register-prefetch commit).
// Pb [i][parity*64+j] wave-private halves. Parity partners combine in the
// epilogue via LDS (round-7-verified). d_ws poison is a fixed harness cost
// -> bf16 prep in ws is free.

typedef __bf16 bf16x8 __attribute__((ext_vector_type(8)));
typedef __bf16 bf16x4 __attribute__((ext_vector_type(4)));
typedef float  f32x4  __attribute__((ext_vector_type(4)));

constexpr int Tn = 1024;
constexpr int Dn = 128;
constexpr int BM = 64;
constexpr int BN = 64;
constexpr int NP = Tn / (2 * BN);   // 8 tile-pairs
constexpr float EPSF = 1e-7f;

// ==================== prep: x fp32 -> Xb bf16, XbT bf16 ====================
__global__ __launch_bounds__(256)
void prep(const float* __restrict__ x, __bf16* __restrict__ Xb,
          __bf16* __restrict__ XbT) {
    __shared__ float tile[64][129];
    const int b = blockIdx.y, t0 = blockIdx.x * 64, t = threadIdx.x;
    #pragma unroll
    for (int k = 0; k < 8; ++k) {
        int cid = t + k * 256;                 // 64 rows x 32 f4-chunks
        int r = cid >> 5, c4 = cid & 31;
        float4 v = *(const float4*)(x + (size_t)(b * Tn + t0 + r) * Dn + c4 * 4);
        bf16x4 bv;
        bv[0] = (__bf16)v.x; bv[1] = (__bf16)v.y; bv[2] = (__bf16)v.z; bv[3] = (__bf16)v.w;
        *(bf16x4*)(Xb + (size_t)(b * Tn + t0 + r) * Dn + c4 * 4) = bv;
        *(float4*)&tile[r][c4 * 4] = v;
    }
    __syncthreads();
    #pragma unroll
    for (int k = 0; k < 2; ++k) {
        int cid = t + k * 256;                 // 128 d x 4 t-chunks(16)
        int dd = cid >> 2, tq = cid & 3;
        bf16x8 v0, v1;
        #pragma unroll
        for (int j = 0; j < 8; ++j) v0[j] = (__bf16)tile[tq * 16 + j][dd];
        #pragma unroll
        for (int j = 0; j < 8; ++j) v1[j] = (__bf16)tile[tq * 16 + 8 + j][dd];
        __bf16* o = XbT + (size_t)(b * Dn + dd) * Tn + t0 + tq * 16;
        *(bf16x8*)o = v0;
        *(bf16x8*)(o + 8) = v1;
    }
}

// ============================ main MFMA kernel ============================
// LDS: KTb[s][d(128)][j(64)]: 16B slot c of row d holds chunk c^(d&7)
//      Pb [i(64)][ p*64 + j ]: within half, slot c of row i holds chunk c^(i&7)
__global__ __launch_bounds__(256, 2)
void attn_mfma(const __bf16* __restrict__ Xb, const __bf16* __restrict__ XbT,
               const int* __restrict__ mask, float* __restrict__ out) {
    __shared__ __align__(16) __bf16 KTb[2][128 * 64];   // 32 KB
    __shared__ __align__(16) __bf16 Pb[64 * 128];       // 16 KB
    __shared__ __align__(16) float mbias[Tn];           // 4 KB

    const int t = threadIdx.x, w = t >> 6, l = t & 63;
    const int m = l & 15, quad = l >> 4;
    const int h = w & 1, p = w >> 1;                    // i-half, j-parity
    const int bid = blockIdx.x;
    const int b = bid & 31, i0 = (bid >> 5) * BM;       // bid%8==b%8: XCD affinity
    const __bf16* xb  = Xb  + (size_t)b * Tn * Dn;
    const __bf16* xtb = XbT + (size_t)b * Dn * Tn;

    // mask bias for all 1024 j
    for (int k = t; k < Tn; k += 256)
        mbias[k] = (mask[b * Tn + k] != 0) ? 0.f : -1e5f;

    // Q fragments: two 16-row groups, i = i0 + h*32 + ig*16 + m
    bf16x8 aq[2][4];
    #pragma unroll
    for (int ig = 0; ig < 2; ++ig) {
        const __bf16* qrow = xb + (size_t)(i0 + h * 32 + ig * 16 + m) * Dn + quad * 8;
        #pragma unroll
        for (int kt = 0; kt < 4; ++kt) aq[ig][kt] = *(const bf16x8*)(qrow + kt * 32);
    }

    // ---- K^T pair staging: wave w covers d-rows w*32..w*32+31 ----
    const int dq = l >> 3, c7 = l & 7;
    bf16x8 kreg[2][4];
    auto load_pair = [&](int pr) {
        const int j0 = pr * 2 * BN;
        #pragma unroll
        for (int s = 0; s < 2; ++s)
            #pragma unroll
            for (int q = 0; q < 4; ++q) {
                const int d = w * 32 + q * 8 + dq;
                const int c = c7 ^ (d & 7);
                kreg[s][q] = *(const bf16x8*)(xtb + (size_t)d * Tn + j0 + s * BN + c * 8);
            }
    };
    auto commit_pair = [&]() {
        #pragma unroll
        for (int s = 0; s < 2; ++s)
            #pragma unroll
            for (int q = 0; q < 4; ++q) {
                const int d = w * 32 + q * 8 + dq;
                *(bf16x8*)(&KTb[s][d * 64 + c7 * 8]) = kreg[s][q];
            }
    };

    load_pair(0);
    commit_pair();
    load_pair(1);

    f32x4 acc[2][8];
    #pragma unroll
    for (int ig = 0; ig < 2; ++ig)
        #pragma unroll
        for (int n2 = 0; n2 < 8; ++n2) acc[ig][n2] = (f32x4){0.f, 0.f, 0.f, 0.f};
    float dsum[2] = {0.f, 0.f};
    const float fi0 = (float)(i0 + h * 32 + m);
    const int irow0 = h * 32 + m;

    __syncthreads();    // prologue commit + mbias visible

    for (int it = 0; it < NP; ++it) {
        const int j0p = it * 2 * BN + p * BN;   // this wave's tile

        // ---- stage 1: S^T = K*Q^T, A-frags from GLOBAL Xb, 1-ahead prefetch ----
        bf16x8 avc[4], avn[4];
        #pragma unroll
        for (int kt = 0; kt < 4; ++kt)
            avc[kt] = *(const bf16x8*)(xb + (size_t)(j0p + m) * Dn + kt * 32 + quad * 8);
        #pragma unroll
        for (int nt = 0; nt < 4; ++nt) {
            if (nt < 3) {
                #pragma unroll
                for (int kt = 0; kt < 4; ++kt)
                    avn[kt] = *(const bf16x8*)(xb +
                        (size_t)(j0p + (nt + 1) * 16 + m) * Dn + kt * 32 + quad * 8);
            }
            f32x4 cs0 = {0.f,0.f,0.f,0.f}, cs1 = {0.f,0.f,0.f,0.f};
            #pragma unroll
            for (int kt = 0; kt < 4; ++kt) {
                cs0 = __builtin_amdgcn_mfma_f32_16x16x32_bf16(avc[kt], aq[0][kt], cs0, 0,0,0);
                cs1 = __builtin_amdgcn_mfma_f32_16x16x32_bf16(avc[kt], aq[1][kt], cs1, 0,0,0);
            }
            // C layout: col = i = m, row = j = nt*16 + quad*4 + r
            const float4 m4 = *(const float4*)&mbias[j0p + nt * 16 + quad * 4];
            const float jb = (float)(j0p + nt * 16 + quad * 4);
            const int jc = nt * 2 + (quad >> 1);
            #pragma unroll
            for (int ig = 0; ig < 2; ++ig) {
                const f32x4 cs = ig ? cs1 : cs0;
                const float base = fi0 + (float)(ig * 16) - jb;
                bf16x4 pv;
                #pragma unroll
                for (int r = 0; r < 4; ++r) {
                    float e = __expf(cs[r] + fminf(base - (float)r, 10.f)
                                     + ((const float*)&m4)[r]);
                    dsum[ig] += e;
                    pv[r] = (__bf16)e;
                }
                const int irow = irow0 + ig * 16;
                *(bf16x4*)(&Pb[irow * 128 + p * 64 +
                               ((jc ^ (irow & 7)) * 8) + (quad & 1) * 4]) = pv;
            }
            if (nt < 3) {
                #pragma unroll
                for (int kt = 0; kt < 4; ++kt) avc[kt] = avn[kt];
            }
        }

        // ---- stage 2: O^T += K^T * P^T (Pb halves wave-private) ----
        bf16x8 ap[2][2];
        #pragma unroll
        for (int ig = 0; ig < 2; ++ig) {
            const int irow = irow0 + ig * 16;
            #pragma unroll
            for (int k2 = 0; k2 < 2; ++k2)
                ap[ig][k2] = *(const bf16x8*)(&Pb[irow * 128 + p * 64 +
                                 (((k2 * 4 + quad) ^ (irow & 7)) * 8)]);
        }
        #pragma unroll
        for (int n2 = 0; n2 < 8; ++n2) {
            const int drow = n2 * 16 + m;
            #pragma unroll
            for (int k2 = 0; k2 < 2; ++k2) {
                bf16x8 av = *(const bf16x8*)(&KTb[p][drow * 64 +
                               (((k2 * 4 + quad) ^ (drow & 7)) * 8)]);
                acc[0][n2] = __builtin_amdgcn_mfma_f32_16x16x32_bf16(av, ap[0][k2], acc[0][n2], 0,0,0);
                acc[1][n2] = __builtin_amdgcn_mfma_f32_16x16x32_bf16(av, ap[1][k2], acc[1][n2], 0,0,0);
            }
        }

        __syncthreads();        // all reads of KTb pair `it` done
        commit_pair();          // pair it+1 -> bufs
        __syncthreads();        // commit visible
        const int nx = (it + 2 < NP) ? it + 2 : NP - 1;
        load_pair(nx);          // overlaps next compute
    }

    // ---- epilogue: combine parity partners (same 32 i, disjoint j) ----
    #pragma unroll
    for (int ig = 0; ig < 2; ++ig) {
        dsum[ig] += __shfl_xor(dsum[ig], 16);
        dsum[ig] += __shfl_xor(dsum[ig], 32);
    }
    __syncthreads();
    float* exf = (float*)&KTb[0][0];     // 32 KB: h*16KB regions
    float* dxf = (float*)&Pb[0];
    if (p == 1) {
        #pragma unroll
        for (int ig = 0; ig < 2; ++ig) {
            #pragma unroll
            for (int n2 = 0; n2 < 8; ++n2)
                *(f32x4*)&exf[h * 4096 + (ig * 8 + n2) * 256 + l * 4] = acc[ig][n2];
            dxf[h * 128 + ig * 64 + l] = dsum[ig];
        }
    }
    __syncthreads();
    if (p == 0) {
        #pragma unroll
        for (int ig = 0; ig < 2; ++ig) {
            #pragma unroll
            for (int n2 = 0; n2 < 8; ++n2)
                acc[ig][n2] += *(const f32x4*)&exf[h * 4096 + (ig * 8 + n2) * 256 + l * 4];
            const float dtot = dsum[ig] + dxf[h * 128 + ig * 64 + l];
            const int i = i0 + h * 32 + ig * 16 + m;
            const float mi = (mask[b * Tn + i] != 0) ? 1.f : 0.f;
            const float inv = mi / (dtot + EPSF);
            float* orow = out + (size_t)(b * Tn + i) * Dn;
            #pragma unroll
            for (int n2 = 0; n2 < 8; ++n2) {
                float4 o;
                o.x = acc[ig][n2][0] * inv; o.y = acc[ig][n2][1] * inv;
                o.z = acc[ig][n2][2] * inv; o.w = acc[ig][n2][3] * inv;
                *(float4*)(orow + n2 * 16 + quad * 4) = o;
            }
        }
    }
}

// ===================== fallback fp32 kernel (no ws) =====================
constexpr int KS = 128;
__device__ __forceinline__ int swz(int row, int c4) { return (c4 ^ ((row >> 2) & 7)); }

__global__ __launch_bounds__(256, 2)
void attn_fused(const float* __restrict__ x, const int* __restrict__ mask,
                float* __restrict__ out) {
    __shared__ float Qs[BM * KS];
    __shared__ float Ks[BN * KS];
    __shared__ float Pt[BN * BM];
    __shared__ float mks[BN];
    const int t = threadIdx.x, b = blockIdx.y, i0 = blockIdx.x * BM;
    const float* xb = x + (size_t)b * Tn * Dn;
    #pragma unroll
    for (int k = 0; k < 8; ++k) {
        int idx = t + k * 256, r = idx >> 5, c4 = idx & 31;
        float4 v = *(const float4*)(xb + (size_t)(i0 + r) * Dn + c4 * 4);
        *(float4*)(&Qs[r * KS + swz(r, c4) * 4]) = v;
    }
    const int sx = t & 15, sy = t >> 4, pc = t & 15, pr = t >> 4;
    float acc[4][8], den[4] = {0.f, 0.f, 0.f, 0.f};
    #pragma unroll
    for (int r = 0; r < 4; ++r)
        #pragma unroll
        for (int c = 0; c < 8; ++c) acc[r][c] = 0.f;
    for (int jt = 0; jt < Tn / BN; ++jt) {
        const int j0 = jt * BN;
        __syncthreads();
        #pragma unroll
        for (int k = 0; k < 8; ++k) {
            int idx = t + k * 256, r = idx >> 5, c4 = idx & 31;
            float4 v = *(const float4*)(xb + (size_t)(j0 + r) * Dn + c4 * 4);
            *(float4*)(&Ks[r * KS + swz(r, c4) * 4]) = v;
        }
        if (t < BN) mks[t] = (mask[b * Tn + j0 + t] != 0) ? 1.0f : 0.0f;
        __syncthreads();
        float s[4][4];
        #pragma unroll
        for (int r = 0; r < 4; ++r)
            #pragma unroll
            for (int c = 0; c < 4; ++c) s[r][c] = 0.f;
        #pragma unroll 4
        for (int d4 = 0; d4 < Dn / 4; ++d4) {
            float4 q[4], kk[4];
            #pragma unroll
            for (int r = 0; r < 4; ++r)
                q[r] = *(const float4*)(&Qs[(4 * sy + r) * KS + (d4 ^ (sy & 7)) * 4]);
            #pragma unroll
            for (int c = 0; c < 4; ++c)
                kk[c] = *(const float4*)(&Ks[(4 * sx + c) * KS + (d4 ^ (sx & 7)) * 4]);
            #pragma unroll
            for (int r = 0; r < 4; ++r)
                #pragma unroll
                for (int c = 0; c < 4; ++c)
                    s[r][c] += q[r].x * kk[c].x + q[r].y * kk[c].y
                             + q[r].z * kk[c].z + q[r].w * kk[c].w;
        }
        #pragma unroll
        for (int r = 0; r < 4; ++r) {
            int i = i0 + 4 * sy + r;
            #pragma unroll
            for (int c = 0; c < 4; ++c) {
                int j = j0 + 4 * sx + c, di = i - j;
                float dist = (float)(di < 10 ? di : 10);
                Pt[(4 * sx + c) * BM + (4 * sy + r)] =
                    __expf(s[r][c] + dist) * mks[4 * sx + c];
            }
        }
        __syncthreads();
        #pragma unroll 4
        for (int j = 0; j < BN; ++j) {
            float4 p4 = *(const float4*)(&Pt[j * BM + 4 * pr]);
            int sw = (j >> 2) & 7;
            float4 k0 = *(const float4*)(&Ks[j * KS + ((2 * pc)     ^ sw) * 4]);
            float4 k1 = *(const float4*)(&Ks[j * KS + ((2 * pc + 1) ^ sw) * 4]);
            float pv[4] = {p4.x, p4.y, p4.z, p4.w};
            #pragma unroll
            for (int r = 0; r < 4; ++r) {
                den[r] += pv[r];
                acc[r][0] += pv[r] * k0.x; acc[r][1] += pv[r] * k0.y;
                acc[r][2] += pv[r] * k0.z; acc[r][3] += pv[r] * k0.w;
                acc[r][4] += pv[r] * k1.x; acc[r][5] += pv[r] * k1.y;
                acc[r][6] += pv[r] * k1.z; acc[r][7] += pv[r] * k1.w;
            }
        }
    }
    const int* mrow = mask + (size_t)b * Tn + i0;
    float* ob = out + ((size_t)b * Tn + i0) * Dn;
    #pragma unroll
    for (int r = 0; r < 4; ++r) {
        int row = 4 * pr + r;
        float mi = (mrow[row] != 0) ? 1.0f : 0.0f;
        float inv = mi / (den[r] + EPSF);
        float4 o0, o1;
        o0.x = acc[r][0] * inv; o0.y = acc[r][1] * inv;
        o0.z = acc[r][2] * inv; o0.w = acc[r][3] * inv;
        o1.x = acc[r][4] * inv; o1.y = acc[r][5] * inv;
        o1.z = acc[r][6] * inv; o1.w = acc[r][7] * inv;
        *(float4*)(&ob[(size_t)row * Dn + 8 * pc    ]) = o0;
        *(float4*)(&ob[(size_t)row * Dn + 8 * pc + 4]) = o1;
    }
}

// ============================ launch ============================
extern "C" void kernel_launch(void* const* d_in, const int* in_sizes, int n_in,
                              void* d_out, int out_size, void* d_ws, size_t ws_size,
                              hipStream_t stream) {
    const float* x    = (const float*)d_in[0];
    const int*   mask = (const int*)d_in[1];
    float*       out  = (float*)d_out;
    const int nx = in_sizes[0];
    const int B  = in_sizes[1] / Tn;

    const size_t need = (size_t)nx * 2 * 2;
    if (ws_size >= need) {
        __bf16* Xb  = (__bf16*)d_ws;
        __bf16* XbT = Xb + nx;
        dim3 pg(Tn / 64, B);
        prep<<<pg, 256, 0, stream>>>(x, Xb, XbT);
        attn_mfma<<<B * (Tn / BM), 256, 0, stream>>>(Xb, XbT, mask, out);
    } else {
        dim3 grid(Tn / BM, B);
        attn_fused<<<grid, 256, 0, stream>>>(x, mask, out);
    }
}